// Round 1
// baseline (272.258 us; speedup 1.0000x reference)
//
#include <hip/hip_runtime.h>

// DGCNN-style fused pipeline: 2x GCNConv + sort-pool(k=70) + 2-layer MLP + sigmoid.
// One block per graph (512 blocks x 256 threads). All intermediates in LDS.

#define NG      512
#define NPG     90
#define EPG     1440
#define IN_DIM  90
#define HD      64
#define KP      70
#define E_TOT   (NG*EPG)

__global__ __launch_bounds__(256, 2) void dgcnn_fused(
    const float* __restrict__ x,     // [46080,90]
    const int*   __restrict__ ei,    // [2,E] int32 (jax x64 disabled -> int32)
    const float* __restrict__ ew,    // [E]
    const float* __restrict__ W1,    // [90,64]
    const float* __restrict__ b1,    // [64]
    const float* __restrict__ W2,    // [64,64]
    const float* __restrict__ b2,    // [64]
    const float* __restrict__ lw1,   // [4480,64]
    const float* __restrict__ lb1,   // [64]
    const float* __restrict__ lw2,   // [64,1]
    const float* __restrict__ lb2,   // [1]
    float* __restrict__ out,         // [512]
    float* __restrict__ xtrain)      // [46080,64]
{
    __shared__ float sB[NPG*HD];          // xw, later hw2
    __shared__ float sC[NPG*HD];          // W1 stage -> h1 -> relu(h1) -> h2
    __shared__ float sW2[HD*HD];
    __shared__ float s_deg[NPG];
    __shared__ float s_dinv[NPG];
    __shared__ int   s_indeg[NPG];
    __shared__ int   s_rowstart[NPG+1];
    __shared__ int   s_cursor[NPG];
    __shared__ unsigned short s_csrc[EPG];
    __shared__ float s_cnorm[EPG];
    __shared__ int   s_ranknode[KP];
    __shared__ float s_zpart[256];

    const int g = blockIdx.x;
    const int t = threadIdx.x;
    const int ebase = g*EPG;
    const int nbase = g*NPG;

    // ---- degree (self-loop weight 1 included) + indegree ----
    for (int i = t; i < NPG; i += 256) { s_deg[i] = 1.0f; s_indeg[i] = 0; }
    __syncthreads();
    for (int e = t; e < EPG; e += 256) {
        int d = ei[E_TOT + ebase + e] - nbase;
        float w = ew[ebase + e];
        atomicAdd(&s_deg[d], w);
        atomicAdd(&s_indeg[d], 1);
    }
    __syncthreads();
    for (int i = t; i < NPG; i += 256) s_dinv[i] = rsqrtf(fmaxf(s_deg[i], 1e-12f));
    if (t == 0) {
        int acc = 0; s_rowstart[0] = 0;
        for (int i = 0; i < NPG; ++i) { acc += s_indeg[i]; s_rowstart[i+1] = acc; }
    }
    __syncthreads();
    for (int i = t; i < NPG; i += 256) s_cursor[i] = s_rowstart[i];
    __syncthreads();

    // ---- CSR fill (by dst), norm = dinv[s]*w*dinv[d] ----
    for (int e = t; e < EPG; e += 256) {
        int s = ei[ebase + e] - nbase;
        int d = ei[E_TOT + ebase + e] - nbase;
        float w = ew[ebase + e];
        int pos = atomicAdd(&s_cursor[d], 1);
        s_csrc[pos]  = (unsigned short)s;
        s_cnorm[pos] = s_dinv[s] * w * s_dinv[d];
    }
    // stage W1 into sC (disjoint from CSR arrays; barrier below covers both)
    for (int i = t; i < IN_DIM*HD; i += 256) sC[i] = W1[i];
    __syncthreads();

    // ---- layer1 matmul: sB = x_g @ W1  (x row is wave-uniform broadcast) ----
    const float* xg = x + (size_t)nbase * IN_DIM;
    for (int o = t; o < NPG*HD; o += 256) {
        int i = o >> 6, j = o & 63;
        const float* xrow = xg + i*IN_DIM;
        float sum = 0.f;
        #pragma unroll 6
        for (int k = 0; k < IN_DIM; ++k) sum += xrow[k] * sC[k*HD + j];
        sB[o] = sum;
    }
    __syncthreads();

    // ---- scatter1: sC = A_hat @ xw + b1  (wave-uniform dst rows, no atomics) ----
    for (int o = t; o < NPG*HD; o += 256) {
        int d = o >> 6, c = o & 63;
        float dv = s_dinv[d];
        float a = dv*dv*sB[o];                      // self loop
        int p0 = s_rowstart[d], p1 = s_rowstart[d+1];
        for (int p = p0; p < p1; ++p) a += s_cnorm[p] * sB[(int)s_csrc[p]*HD + c];
        sC[o] = a + b1[c];
    }
    __syncthreads();

    // ---- x_train out (pre-relu), relu in place; stage W2 ----
    float* xt = xtrain + (size_t)nbase * HD;
    for (int o = t; o < NPG*HD; o += 256) {
        float v = sC[o];
        xt[o] = v;
        sC[o] = fmaxf(v, 0.f);
    }
    for (int i = t; i < HD*HD; i += 256) sW2[i] = W2[i];
    __syncthreads();

    // ---- layer2 matmul: sB = relu(h1) @ W2 ----
    for (int o = t; o < NPG*HD; o += 256) {
        int i = o >> 6, j = o & 63;
        float sum = 0.f;
        #pragma unroll
        for (int k = 0; k < HD; ++k) sum += sC[i*HD + k] * sW2[k*HD + j];
        sB[o] = sum;
    }
    __syncthreads();

    // ---- scatter2: sC = A_hat @ hw2 + b2 ----
    for (int o = t; o < NPG*HD; o += 256) {
        int d = o >> 6, c = o & 63;
        float dv = s_dinv[d];
        float a = dv*dv*sB[o];
        int p0 = s_rowstart[d], p1 = s_rowstart[d+1];
        for (int p = p0; p < p1; ++p) a += s_cnorm[p] * sB[(int)s_csrc[p]*HD + c];
        sC[o] = a + b2[c];
    }
    __syncthreads();

    // ---- sort-pool: stable descending rank by channel 63 (matches argsort(-v)) ----
    if (t < NPG) {
        float vi = sC[t*HD + (HD-1)];
        int rank = 0;
        for (int j = 0; j < NPG; ++j) {
            float vj = sC[j*HD + (HD-1)];      // broadcast read
            rank += (vj > vi) || (vj == vi && j < t);
        }
        if (rank < KP) s_ranknode[rank] = t;
    }
    __syncthreads();

    // ---- MLP: z[j] = sum_{k<70,c<64} h2[node(k)][c] * lw1[(k*64+c)*64+j] ----
    {
        int j = t & 63, kp = t >> 6;            // 4-way split over k
        float partial = 0.f;
        for (int k = kp; k < KP; k += 4) {
            int node = s_ranknode[k];
            const float* prow = &sC[node*HD];
            const float* wrow = lw1 + (size_t)(k*HD)*HD + j;
            #pragma unroll 8
            for (int c = 0; c < HD; ++c) partial += prow[c] * wrow[(size_t)c*HD];
        }
        s_zpart[t] = partial;
    }
    __syncthreads();

    if (t < 64) {
        float z1 = s_zpart[t] + s_zpart[t+64] + s_zpart[t+128] + s_zpart[t+192] + lb1[t];
        float zz = z1 * lw2[t];
        #pragma unroll
        for (int off = 32; off > 0; off >>= 1) zz += __shfl_down(zz, off, 64);
        if (t == 0) out[g] = 1.0f / (1.0f + expf(-(zz + lb2[0])));
    }
}

extern "C" void kernel_launch(void* const* d_in, const int* in_sizes, int n_in,
                              void* d_out, int out_size, void* d_ws, size_t ws_size,
                              hipStream_t stream) {
    const float* x   = (const float*)d_in[0];
    const int*   ei  = (const int*)  d_in[1];
    const float* ew  = (const float*)d_in[2];
    // d_in[3] = batch (unused; graphs are contiguous 90-node blocks)
    const float* W1  = (const float*)d_in[4];
    const float* b1  = (const float*)d_in[5];
    const float* W2  = (const float*)d_in[6];
    const float* b2  = (const float*)d_in[7];
    const float* lw1 = (const float*)d_in[8];
    const float* lb1 = (const float*)d_in[9];
    const float* lw2 = (const float*)d_in[10];
    const float* lb2 = (const float*)d_in[11];

    float* out    = (float*)d_out;        // [512]
    float* xtrain = out + NG;             // [46080*64]

    dgcnn_fused<<<NG, 256, 0, stream>>>(x, ei, ew, W1, b1, W2, b2,
                                        lw1, lb1, lw2, lb2, out, xtrain);
}

// Round 2
// 192.657 us; speedup vs baseline: 1.4132x; 1.4132x over previous
//
#include <hip/hip_runtime.h>

// DGCNN fused: 2x GCNConv + sort-pool(k=70) + MLP + sigmoid.
// One block per graph, 512 threads (8 waves), 2 blocks/CU resident.

#define NG      512
#define NPG     90
#define EPG     1440
#define IN_DIM  90
#define HD      64
#define KP      70
#define E_TOT   (NG*EPG)
#define NT      512

__global__ __launch_bounds__(NT, 4) void dgcnn_fused(
    const float* __restrict__ x,     // [46080,90]
    const int*   __restrict__ ei,    // [2,E]
    const float* __restrict__ ew,    // [E]
    const float* __restrict__ W1,    // [90,64]
    const float* __restrict__ b1,    // [64]
    const float* __restrict__ W2,    // [64,64]
    const float* __restrict__ b2,    // [64]
    const float* __restrict__ lw1,   // [4480,64]
    const float* __restrict__ lb1,   // [64]
    const float* __restrict__ lw2,   // [64,1]
    const float* __restrict__ lb2,   // [1]
    float* __restrict__ out,         // [512]
    float* __restrict__ xtrain)      // [46080,64]
{
    __shared__ float sB[NPG*HD];           // xw / hw2
    __shared__ float sC[NPG*HD];           // W1 stage -> h1 -> relu -> h2
    __shared__ float sW2[HD*HD];
    __shared__ float s_deg[NPG];
    __shared__ float s_dinv[NPG];
    __shared__ int   s_indeg[NPG];
    __shared__ int   s_rowstart[NPG+1];
    __shared__ int   s_cursor[NPG];
    __shared__ float2 s_cpack[EPG];        // {norm, as_float(src)}
    __shared__ int   s_ranknode[KP];
    __shared__ float s_zpart[NT];

    const int g = blockIdx.x;
    const int t = threadIdx.x;
    const int j = t & 63;                  // lane within wave
    const int grp = t >> 6;                // wave id 0..7
    const int ebase = g*EPG;
    const int nbase = g*NPG;

    // ---- phase 0: init ----
    if (t < NPG) { s_deg[t] = 1.0f; s_indeg[t] = 0; }
    __syncthreads();

    // ---- phase 1: degree + indegree ----
    for (int e = t; e < EPG; e += NT) {
        int d = ei[E_TOT + ebase + e] - nbase;
        float w = ew[ebase + e];
        atomicAdd(&s_deg[d], w);
        atomicAdd(&s_indeg[d], 1);
    }
    __syncthreads();

    // ---- phase 2: dinv + parallel prefix scan + cursor ----
    if (t < NPG) s_dinv[t] = rsqrtf(fmaxf(s_deg[t], 1e-12f));
    if (t <= NPG) {
        int acc = 0;
        for (int i = 0; i < t; ++i) acc += s_indeg[i];   // independent reads, pipelined
        s_rowstart[t] = acc;
        if (t < NPG) s_cursor[t] = acc;
    }
    __syncthreads();

    // ---- phase 3: CSR fill (packed) + stage W1 into sC ----
    for (int e = t; e < EPG; e += NT) {
        int s = ei[ebase + e] - nbase;
        int d = ei[E_TOT + ebase + e] - nbase;
        float w = ew[ebase + e];
        int pos = atomicAdd(&s_cursor[d], 1);
        s_cpack[pos] = make_float2(s_dinv[s] * w * s_dinv[d], __int_as_float(s));
    }
    for (int i4 = t; i4 < IN_DIM*HD/4; i4 += NT)
        ((float4*)sC)[i4] = ((const float4*)W1)[i4];
    __syncthreads();

    // ---- phase 4: layer1 matmul sB = x_g @ W1, 4 rows/thread ----
    const float* xg = x + (size_t)nbase * IN_DIM;
    for (int it = 0; it < 3; ++it) {
        int r0 = it*32 + grp*4;
        int rr0 = min(r0+0, NPG-1), rr1 = min(r0+1, NPG-1);
        int rr2 = min(r0+2, NPG-1), rr3 = min(r0+3, NPG-1);
        const float2* xp0 = (const float2*)(xg + rr0*IN_DIM);
        const float2* xp1 = (const float2*)(xg + rr1*IN_DIM);
        const float2* xp2 = (const float2*)(xg + rr2*IN_DIM);
        const float2* xp3 = (const float2*)(xg + rr3*IN_DIM);
        float a0 = 0.f, a1 = 0.f, a2 = 0.f, a3 = 0.f;
        #pragma unroll 9
        for (int kh = 0; kh < IN_DIM/2; ++kh) {
            float w0 = sC[(2*kh)*HD + j];
            float w1 = sC[(2*kh+1)*HD + j];
            float2 v0 = xp0[kh], v1 = xp1[kh], v2 = xp2[kh], v3 = xp3[kh];
            a0 += v0.x*w0 + v0.y*w1;
            a1 += v1.x*w0 + v1.y*w1;
            a2 += v2.x*w0 + v2.y*w1;
            a3 += v3.x*w0 + v3.y*w1;
        }
        if (r0+0 < NPG) sB[(r0+0)*HD + j] = a0;
        if (r0+1 < NPG) sB[(r0+1)*HD + j] = a1;
        if (r0+2 < NPG) sB[(r0+2)*HD + j] = a2;
        if (r0+3 < NPG) sB[(r0+3)*HD + j] = a3;
    }
    __syncthreads();

    // ---- phase 5: scatter1 sC = A_hat @ xw + b1 (dst wave-uniform) ----
    for (int o = t; o < NPG*HD; o += NT) {
        int d = o >> 6, c = o & 63;
        float dv = s_dinv[d];
        float a = dv*dv*sB[o];
        int p0 = s_rowstart[d], p1 = s_rowstart[d+1];
        for (int p = p0; p < p1; ++p) {
            float2 pk = s_cpack[p];
            a += pk.x * sB[__float_as_int(pk.y)*HD + c];
        }
        sC[o] = a + b1[c];
    }
    __syncthreads();

    // ---- phase 6: xtrain store (pre-relu) + relu in place + stage W2 ----
    float* xt = xtrain + (size_t)nbase * HD;
    for (int i4 = t; i4 < NPG*HD/4; i4 += NT) {
        float4 v = ((float4*)sC)[i4];
        ((float4*)xt)[i4] = v;
        v.x = fmaxf(v.x, 0.f); v.y = fmaxf(v.y, 0.f);
        v.z = fmaxf(v.z, 0.f); v.w = fmaxf(v.w, 0.f);
        ((float4*)sC)[i4] = v;
    }
    for (int i4 = t; i4 < HD*HD/4; i4 += NT)
        ((float4*)sW2)[i4] = ((const float4*)W2)[i4];
    __syncthreads();

    // ---- phase 7: layer2 matmul sB = relu(h1) @ W2, 4 rows/thread ----
    for (int it = 0; it < 3; ++it) {
        int r0 = it*32 + grp*4;
        int rr0 = min(r0+0, NPG-1), rr1 = min(r0+1, NPG-1);
        int rr2 = min(r0+2, NPG-1), rr3 = min(r0+3, NPG-1);
        float a0 = 0.f, a1 = 0.f, a2 = 0.f, a3 = 0.f;
        #pragma unroll 4
        for (int k4 = 0; k4 < HD/4; ++k4) {
            int k = k4*4;
            float4 h0 = *(const float4*)&sC[rr0*HD + k];
            float4 h1 = *(const float4*)&sC[rr1*HD + k];
            float4 h2 = *(const float4*)&sC[rr2*HD + k];
            float4 h3 = *(const float4*)&sC[rr3*HD + k];
            float w0 = sW2[(k+0)*HD + j];
            float w1 = sW2[(k+1)*HD + j];
            float w2 = sW2[(k+2)*HD + j];
            float w3 = sW2[(k+3)*HD + j];
            a0 += h0.x*w0 + h0.y*w1 + h0.z*w2 + h0.w*w3;
            a1 += h1.x*w0 + h1.y*w1 + h1.z*w2 + h1.w*w3;
            a2 += h2.x*w0 + h2.y*w1 + h2.z*w2 + h2.w*w3;
            a3 += h3.x*w0 + h3.y*w1 + h3.z*w2 + h3.w*w3;
        }
        if (r0+0 < NPG) sB[(r0+0)*HD + j] = a0;
        if (r0+1 < NPG) sB[(r0+1)*HD + j] = a1;
        if (r0+2 < NPG) sB[(r0+2)*HD + j] = a2;
        if (r0+3 < NPG) sB[(r0+3)*HD + j] = a3;
    }
    __syncthreads();

    // ---- phase 8: scatter2 sC = A_hat @ hw2 + b2 ----
    for (int o = t; o < NPG*HD; o += NT) {
        int d = o >> 6, c = o & 63;
        float dv = s_dinv[d];
        float a = dv*dv*sB[o];
        int p0 = s_rowstart[d], p1 = s_rowstart[d+1];
        for (int p = p0; p < p1; ++p) {
            float2 pk = s_cpack[p];
            a += pk.x * sB[__float_as_int(pk.y)*HD + c];
        }
        sC[o] = a + b2[c];
    }
    __syncthreads();

    // ---- phase 9: sort-pool rank (stable descending on channel 63) ----
    if (t < NPG) {
        float vi = sC[t*HD + (HD-1)];
        int rank = 0;
        for (int jj = 0; jj < NPG; ++jj) {
            float vj = sC[jj*HD + (HD-1)];
            rank += (vj > vi) || (vj == vi && jj < t);
        }
        if (rank < KP) s_ranknode[rank] = t;
    }
    __syncthreads();

    // ---- phase 10: MLP partials: 8-way split over k ----
    {
        float partial = 0.f;
        for (int k = grp; k < KP; k += 8) {
            int node = s_ranknode[k];
            const float4* prow = (const float4*)&sC[node*HD];
            const float* wrow = lw1 + (size_t)(k*HD)*HD + j;
            #pragma unroll 4
            for (int c4 = 0; c4 < HD/4; ++c4) {
                float4 pv = prow[c4];
                int c = c4*4;
                partial += pv.x * wrow[(size_t)(c+0)*HD];
                partial += pv.y * wrow[(size_t)(c+1)*HD];
                partial += pv.z * wrow[(size_t)(c+2)*HD];
                partial += pv.w * wrow[(size_t)(c+3)*HD];
            }
        }
        s_zpart[t] = partial;
    }
    __syncthreads();

    if (t < HD) {
        float z1 = lb1[t];
        #pragma unroll
        for (int m = 0; m < NT/HD; ++m) z1 += s_zpart[t + m*HD];
        float zz = z1 * lw2[t];
        #pragma unroll
        for (int off = 32; off > 0; off >>= 1) zz += __shfl_down(zz, off, 64);
        if (t == 0) out[g] = 1.0f / (1.0f + expf(-(zz + lb2[0])));
    }
}

extern "C" void kernel_launch(void* const* d_in, const int* in_sizes, int n_in,
                              void* d_out, int out_size, void* d_ws, size_t ws_size,
                              hipStream_t stream) {
    const float* x   = (const float*)d_in[0];
    const int*   ei  = (const int*)  d_in[1];
    const float* ew  = (const float*)d_in[2];
    const float* W1  = (const float*)d_in[4];
    const float* b1  = (const float*)d_in[5];
    const float* W2  = (const float*)d_in[6];
    const float* b2  = (const float*)d_in[7];
    const float* lw1 = (const float*)d_in[8];
    const float* lb1 = (const float*)d_in[9];
    const float* lw2 = (const float*)d_in[10];
    const float* lb2 = (const float*)d_in[11];

    float* out    = (float*)d_out;        // [512]
    float* xtrain = out + NG;             // [46080*64]

    dgcnn_fused<<<NG, NT, 0, stream>>>(x, ei, ew, W1, b1, W2, b2,
                                       lw1, lb1, lw2, lb2, out, xtrain);
}